// Round 5
// baseline (16304.356 us; speedup 1.0000x reference)
//
#include <hip/hip_runtime.h>
#include <math.h>

#define T_ 1024
#define B_ 512
#define I_ 128
#define H_ 256
#define K_ 384
#define GSIZE 8    /* blocks per group */
#define GB 16      /* batches per group */
#define US 32      /* units per block slice */
#define NROWS 128  /* gate rows per block = 4*US */
#define VPAD 392   /* padded row length (halves): 784 B, 196 words % 32 = 4 */

typedef _Float16 half8 __attribute__((ext_vector_type(8)));
typedef float float4v __attribute__((ext_vector_type(4)));
typedef unsigned long long u64;

__device__ __forceinline__ float fsigmoid(float x) {
  return 1.0f / (1.0f + __expf(-x));
}
__device__ __forceinline__ float ftanh(float x) {
  float ax = fabsf(x);
  float e = __expf(-2.0f * ax);
  float t = (1.0f - e) / (1.0f + e);
  return copysignf(t, x);
}

// ws layout (bytes):
//   wh16  [1024][384] _Float16 : 0        .. 786432
//   biasq [256] float4         : 786432   .. 790528
//   hbuf  [2][512][256] f16    : 790528   .. 1314816
//   flags [256] uint           : 1314816  .. 1315840
#define WS_WH 0
#define WS_BIAS 786432
#define WS_HBUF 790528
#define WS_FLAG 1314816

// ---------------------------------------------------------------------------
// prep: fp16-pack fused weights row-major [1024][384], gather biases,
// zero hbuf / flags / out. grid 1024 x 384.
// ---------------------------------------------------------------------------
__global__ void prep_kernel(const float* __restrict__ W_ih,
                            const float* __restrict__ W_hh,
                            const float* __restrict__ b_ih,
                            const float* __restrict__ b_hh,
                            char* __restrict__ ws,
                            float* __restrict__ out) {
  _Float16* wh16 = (_Float16*)(ws + WS_WH);
  float4* biasq = (float4*)(ws + WS_BIAS);
  unsigned* hb32 = (unsigned*)(ws + WS_HBUF);
  unsigned* flags = (unsigned*)(ws + WS_FLAG);
  const int r = (int)blockIdx.x;   // W_fused row 0..1023
  const int k = (int)threadIdx.x;  // 0..383
  const float w = (k < I_) ? W_ih[r * I_ + k] : W_hh[r * H_ + (k - I_)];
  wh16[r * K_ + k] = (_Float16)w;
  if (r < H_ && k == 0) {
    biasq[r] = make_float4(b_ih[r] + b_hh[r],
                           b_ih[H_ + r] + b_hh[H_ + r],
                           b_ih[2 * H_ + r] + b_hh[2 * H_ + r],
                           b_ih[3 * H_ + r] + b_hh[3 * H_ + r]);
  }
  const int gi = r * 384 + k;
  if (gi < 131072) hb32[gi] = 0u;  // zero both hbuf parities (524288 B)
  if (gi < 256) flags[gi] = 0u;
  if (gi < B_) out[gi] = 0.0f;
}

// ---------------------------------------------------------------------------
// main: 256 blocks x 256 threads, 1 block/CU (LDS ~121 KB forces it).
// Group = 8 blocks stride-8 in blockIdx (same-XCD heuristic). Each block:
// LDS-resident 128x384 fp16 weight slice; per step MFMA 16x128 gate tile,
// lane-local activations, h-slice exchange through global + flag release.
// ---------------------------------------------------------------------------
__global__ __launch_bounds__(256) void lstm_kernel(
    const float* __restrict__ x,      // [T,B,I] fp32
    const float* __restrict__ W_out,  // [H]
    const float* __restrict__ b_out,  // [1]
    char* __restrict__ ws,
    float* __restrict__ out) {        // [B], prep-zeroed, atomicAdd
  const _Float16* __restrict__ wh16 = (const _Float16*)(ws + WS_WH);
  const float4* __restrict__ biasq = (const float4*)(ws + WS_BIAS);
  _Float16* __restrict__ hbuf = (_Float16*)(ws + WS_HBUF);
  unsigned* __restrict__ flags = (unsigned*)(ws + WS_FLAG);

  __shared__ __align__(16) _Float16 wmat[NROWS][VPAD];  // 100352 B
  __shared__ __align__(16) _Float16 v[GB][VPAD];        // 12544 B
  __shared__ __align__(16) float cpart[2][64][16];      // 8192 B (waves 2,3)
  __shared__ float msk2[2][GB];
  __shared__ float opart[GB];

  const int tid = (int)threadIdx.x;
  const int bid = (int)blockIdx.x;
  const int cc = bid & 7;        // XCD congruence class
  const int rr = bid >> 3;       // 0..31
  const int qq = rr >> 3;        // 0..3
  const int mm = rr & 7;         // member in group = slice
  const int gid = cc * 4 + qq;   // group 0..31
  const int gb0 = gid * GB;      // first batch of group
  const int slice = mm;

  const int wave = tid >> 6;
  const int lane = tid & 63;
  const int quad = lane >> 4;  // 0..3
  const int col = lane & 15;   // 0..15
  const int ng = wave & 1;     // unit sub-slice (0: units 0-15, 1: 16-31)
  const int kh = wave >> 1;    // K half

  // ---- fill wmat: row n = g*32 + ul  <->  global row g*256 + slice*32 + ul
  {
    const int n = tid >> 1, hp = tid & 1;
    const int g = n >> 5, ul = n & 31;
    const int grow = g * H_ + slice * US + ul;
    const uint4* src = (const uint4*)(wh16 + (size_t)grow * K_ + hp * 192);
    uint4* dst = (uint4*)&wmat[n][hp * 192];
#pragma unroll 4
    for (int i = 0; i < 24; ++i) dst[i] = src[i];
  }

  // per-lane activation ownership (waves 0,1): unit ng*16+col, batches quad*4+r
  const int gu = slice * US + ng * 16 + col;  // global unit
  float4 bias = make_float4(0.f, 0.f, 0.f, 0.f);
  if (wave < 2) bias = biasq[gu];
  float c_st[4] = {0.f, 0.f, 0.f, 0.f};
  float lasth[4] = {0.f, 0.f, 0.f, 0.f};

  __syncthreads();  // wmat ready

  const int xb = tid >> 4;  // staging: batch 0..15
  const int xc = tid & 15;  // chunk

  for (int t = 0; t < T_; ++t) {
    // ---- stage x_t (fp32 -> fp16) into v[:, 0:128], mask from fp32 x[...,127]
    {
      const float4* xp =
          (const float4*)(x + ((long)t * B_ + (gb0 + xb)) * I_ + xc * 8);
      const float4 x1 = xp[0], x2 = xp[1];
      half8 hx;
      hx[0] = (_Float16)x1.x; hx[1] = (_Float16)x1.y;
      hx[2] = (_Float16)x1.z; hx[3] = (_Float16)x1.w;
      hx[4] = (_Float16)x2.x; hx[5] = (_Float16)x2.y;
      hx[6] = (_Float16)x2.z; hx[7] = (_Float16)x2.w;
      *(half8*)&v[xb][xc * 8] = hx;
      if (xc == 15) msk2[t & 1][xb] = (x2.w > 0.0f) ? 1.0f : 0.0f;
    }
    // ---- wait peers published h(t-1)
    if (tid < GSIZE - 1) {
      const int mp = tid + (tid >= mm ? 1 : 0);
      const int peer = cc + 8 * (qq * 8 + mp);
      while (__hip_atomic_load(&flags[peer], __ATOMIC_RELAXED,
                               __HIP_MEMORY_SCOPE_AGENT) < (unsigned)t)
        __builtin_amdgcn_s_sleep(1);
    }
    __syncthreads();  // S1: spin done, x staged
    __builtin_amdgcn_fence(__ATOMIC_ACQUIRE, "agent");
    // ---- load h(t-1) (all 256 units, L2-coherent atomic u64) into v[:,128:384]
    {
      const u64* hp8 =
          (const u64*)(hbuf + (size_t)(((t + 1) & 1) * B_ + gb0 + xb) * H_ +
                       xc * 16);
#pragma unroll
      for (int i = 0; i < 4; ++i) {
        u64 hv = __hip_atomic_load(hp8 + i, __ATOMIC_RELAXED,
                                   __HIP_MEMORY_SCOPE_AGENT);
        *(u64*)&v[xb][I_ + xc * 16 + 4 * i] = hv;
      }
    }
    __syncthreads();  // S2: v complete

    // ---- MFMA: C[16 batches][128 gate rows], wave (ng,kh) does 4 N-tiles x 6 K
    float4v acc[4] = {(float4v)(0.f), (float4v)(0.f), (float4v)(0.f),
                      (float4v)(0.f)};
#pragma unroll
    for (int kt = kh * 6; kt < kh * 6 + 6; ++kt) {
      const half8 a8 = *(const half8*)&v[col][kt * 32 + quad * 8];
#pragma unroll
      for (int g = 0; g < 4; ++g) {
        const int nrow = g * US + ng * 16 + col;
        const half8 b8 = *(const half8*)&wmat[nrow][kt * 32 + quad * 8];
        acc[g] = __builtin_amdgcn_mfma_f32_16x16x32_f16(a8, b8, acc[g], 0, 0, 0);
      }
    }
    if (wave >= 2) {  // publish K-half-1 partials
#pragma unroll
      for (int g = 0; g < 4; ++g)
        *(float4v*)&cpart[wave - 2][lane][g * 4] = acc[g];
    }
    __syncthreads();  // S3: partials visible

    if (wave < 2) {  // ---- reduce + activation + h store
      float4v s[4];
#pragma unroll
      for (int g = 0; g < 4; ++g)
        s[g] = acc[g] + *(const float4v*)&cpart[wave][lane][g * 4];
#pragma unroll
      for (int r = 0; r < 4; ++r) {
        const int bloc = quad * 4 + r;
        const float m = msk2[t & 1][bloc];
        const float gi = fsigmoid(s[0][r] + bias.x);
        const float gf = fsigmoid(s[1][r] + bias.y);
        const float gg = ftanh(s[2][r] + bias.z);
        const float go = fsigmoid(s[3][r] + bias.w);
        const float cn = gf * c_st[r] + gi * gg;
        const float hn = go * ftanh(cn);
        if (t == T_ - 1) lasth[r] = hn;  // hs[-1] is UNMASKED h_new
        c_st[r] = m * cn;
        hbuf[(size_t)((t & 1) * B_ + gb0 + bloc) * H_ + gu] =
            (_Float16)(m * hn);
      }
    }
    __syncthreads();  // S4: h stores drained (vmcnt(0) before barrier)
    if (tid == 0) {
      __builtin_amdgcn_fence(__ATOMIC_RELEASE, "agent");
      __hip_atomic_store(&flags[bid], (unsigned)(t + 1), __ATOMIC_RELAXED,
                         __HIP_MEMORY_SCOPE_AGENT);
    }
  }

  // ---- output: likelihood[b] = sum_u W_out[u]*lasth[b][u] + b_out
  if (tid < GB) opart[tid] = 0.0f;
  __syncthreads();
  if (wave < 2) {
    const float wo = W_out[gu];
#pragma unroll
    for (int r = 0; r < 4; ++r)
      atomicAdd(&opart[quad * 4 + r], wo * lasth[r]);
  }
  __syncthreads();
  if (tid < GB)
    atomicAdd(&out[gb0 + tid],
              opart[tid] + (slice == 0 ? b_out[0] : 0.0f));
}

extern "C" void kernel_launch(void* const* d_in, const int* in_sizes, int n_in,
                              void* d_out, int out_size, void* d_ws,
                              size_t ws_size, hipStream_t stream) {
  (void)in_sizes; (void)n_in; (void)out_size; (void)ws_size;
  const float* x     = (const float*)d_in[0];
  const float* W_ih  = (const float*)d_in[1];
  const float* W_hh  = (const float*)d_in[2];
  const float* b_ih  = (const float*)d_in[3];
  const float* b_hh  = (const float*)d_in[4];
  const float* W_out = (const float*)d_in[5];
  const float* b_out = (const float*)d_in[6];
  float* out = (float*)d_out;
  char* ws = (char*)d_ws;

  hipLaunchKernelGGL(prep_kernel, dim3(4 * H_), dim3(K_), 0, stream,
                     W_ih, W_hh, b_ih, b_hh, ws, out);
  hipLaunchKernelGGL(lstm_kernel, dim3(256), dim3(256), 0, stream,
                     x, W_out, b_out, ws, out);
}